// Round 4
// baseline (81.651 us; speedup 1.0000x reference)
//
#include <hip/hip_runtime.h>

// Input:  x (8, 32, 512, 512) fp32  -> 256 images of 512x512
// Output: LL,LH,HL,HH each (8, 32, 256, 256) fp32, concatenated flat.
//
// 2x2 output tile per thread: input rows 4j..4j+3, cols 8g..8g+7
// -> output rows 2j,2j+1, cols 4g..4g+3 in each plane.
// 8 loads + 8 nontemporal stores per thread (full-line wave store runs).

#define N_IMG   256u
#define IN_W    512u
#define OUT_W   256u
#define PLANE   (N_IMG * OUT_W * OUT_W)

typedef float f4 __attribute__((ext_vector_type(4)));

__device__ __forceinline__ void haar_row(const f4 a, const f4 b,
                                         const f4 c, const f4 d,
                                         f4* ll, f4* lh, f4* hl, f4* hh)
{
    // a = row0 cols 0..3, b = row0 cols 4..7, c = row1 cols 0..3, d = row1 cols 4..7
    ll->x = (a.x + a.y + c.x + c.y) * 0.5f;
    lh->x = (a.x + a.y - c.x - c.y) * 0.5f;
    hl->x = (a.x - a.y + c.x - c.y) * 0.5f;
    hh->x = (a.x - a.y - c.x + c.y) * 0.5f;

    ll->y = (a.z + a.w + c.z + c.w) * 0.5f;
    lh->y = (a.z + a.w - c.z - c.w) * 0.5f;
    hl->y = (a.z - a.w + c.z - c.w) * 0.5f;
    hh->y = (a.z - a.w - c.z + c.w) * 0.5f;

    ll->z = (b.x + b.y + d.x + d.y) * 0.5f;
    lh->z = (b.x + b.y - d.x - d.y) * 0.5f;
    hl->z = (b.x - b.y + d.x - d.y) * 0.5f;
    hh->z = (b.x - b.y - d.x + d.y) * 0.5f;

    ll->w = (b.z + b.w + d.z + d.w) * 0.5f;
    lh->w = (b.z + b.w - d.z - d.w) * 0.5f;
    hl->w = (b.z - b.w + d.z - d.w) * 0.5f;
    hh->w = (b.z - b.w - d.z + d.w) * 0.5f;
}

__global__ __launch_bounds__(256) void dwt2d_haar_kernel(
    const float* __restrict__ x, float* __restrict__ out)
{
    unsigned t = blockIdx.x * 256u + threadIdx.x;
    // per image: 128 row-pairs * 64 quad-col groups = 8192 threads
    unsigned img = t >> 13;
    unsigned rem = t & 8191u;
    unsigned j   = rem >> 6;       // output row pair 0..127 (out rows 2j, 2j+1)
    unsigned g   = rem & 63u;      // quad-col group 0..63 (input cols 8g..8g+7)

    const float* rowbase = x + (size_t)img * (IN_W * IN_W)
                             + (size_t)(4u * j) * IN_W + 8u * g;

    // 8 independent loads (rows 4j..4j+3, two f4 each)
    f4 r0a = *reinterpret_cast<const f4*>(rowbase);
    f4 r0b = *reinterpret_cast<const f4*>(rowbase + 4);
    f4 r1a = *reinterpret_cast<const f4*>(rowbase + IN_W);
    f4 r1b = *reinterpret_cast<const f4*>(rowbase + IN_W + 4);
    f4 r2a = *reinterpret_cast<const f4*>(rowbase + 2 * IN_W);
    f4 r2b = *reinterpret_cast<const f4*>(rowbase + 2 * IN_W + 4);
    f4 r3a = *reinterpret_cast<const f4*>(rowbase + 3 * IN_W);
    f4 r3b = *reinterpret_cast<const f4*>(rowbase + 3 * IN_W + 4);

    f4 ll0, lh0, hl0, hh0, ll1, lh1, hl1, hh1;
    haar_row(r0a, r0b, r1a, r1b, &ll0, &lh0, &hl0, &hh0);
    haar_row(r2a, r2b, r3a, r3b, &ll1, &lh1, &hl1, &hh1);

    size_t oidx = (size_t)img * (OUT_W * OUT_W) + (size_t)(2u * j) * OUT_W + 4u * g;
    float* o0 = out + 0ull * PLANE + oidx;
    float* o1 = out + 1ull * PLANE + oidx;
    float* o2 = out + 2ull * PLANE + oidx;
    float* o3 = out + 3ull * PLANE + oidx;

    __builtin_nontemporal_store(ll0, reinterpret_cast<f4*>(o0));
    __builtin_nontemporal_store(lh0, reinterpret_cast<f4*>(o1));
    __builtin_nontemporal_store(hl0, reinterpret_cast<f4*>(o2));
    __builtin_nontemporal_store(hh0, reinterpret_cast<f4*>(o3));
    __builtin_nontemporal_store(ll1, reinterpret_cast<f4*>(o0 + OUT_W));
    __builtin_nontemporal_store(lh1, reinterpret_cast<f4*>(o1 + OUT_W));
    __builtin_nontemporal_store(hl1, reinterpret_cast<f4*>(o2 + OUT_W));
    __builtin_nontemporal_store(hh1, reinterpret_cast<f4*>(o3 + OUT_W));
}

extern "C" void kernel_launch(void* const* d_in, const int* in_sizes, int n_in,
                              void* d_out, int out_size, void* d_ws, size_t ws_size,
                              hipStream_t stream) {
    const float* x = (const float*)d_in[0];
    float* out = (float*)d_out;
    // total threads = 256 images * 8192 = 2,097,152 -> 8192 blocks of 256
    dim3 grid(8192), block(256);
    hipLaunchKernelGGL(dwt2d_haar_kernel, grid, block, 0, stream, x, out);
}